// Round 1
// baseline (204.005 us; speedup 1.0000x reference)
//
#include <hip/hip_runtime.h>
#include <math.h>

// CTransformer: B=4, C=256, H=W=64, NHEAD=8 (dh=32), 3x3 windows stride 1 pad 1,
// only the center token of each window reaches the output.
//
// Pipeline (all fp32 this round, correctness-first):
//   k_pads    : pad_k/pad_v vectors for out-of-bounds neighbors (LN(0) = ln_b)
//   k_ln      : per-pixel LayerNorm over C, layout-preserving [B][C][HW]
//   k_gemm_qkv: qkv[n][d] = sum_c x2[c][n] * Wqkv[d][c] + bqkv[d]   (16384x768x256)
//   k_attn    : per-pixel 9-neighbor attention, 8 heads, shuffle-reduced scores
//   k_outproj : out[n][d] = sum_c o[n][c] * Wout[d][c] + bout[d]; +src residual,
//               transposed store back to [B][C][H][W]

#define NPIX 16384   // B * H * W
#define HW   4096
#define CDIM 256

__global__ void k_pads(const float* __restrict__ Wqkv, const float* __restrict__ bqkv,
                       const float* __restrict__ lnb, float* __restrict__ pads) {
    int d = threadIdx.x;            // 0..511 ; 0..255 -> pad_k, 256..511 -> pad_v
    int row = 256 + d;              // k rows 256..511, v rows 512..767
    const float* wrow = Wqkv + (size_t)row * CDIM;
    float s = bqkv[row];
    for (int c = 0; c < CDIM; ++c) s += lnb[c] * wrow[c];
    pads[d] = s;
}

__global__ __launch_bounds__(256) void k_ln(const float* __restrict__ src,
                                            const float* __restrict__ lnw,
                                            const float* __restrict__ lnb,
                                            float* __restrict__ x2) {
    int n = blockIdx.x * 256 + threadIdx.x;   // pixel index (coalesced: p fastest)
    int b = n >> 12;
    int p = n & 4095;
    const float* sp = src + ((size_t)b * CDIM) * HW + p;
    float sum = 0.f, sq = 0.f;
    for (int c = 0; c < CDIM; ++c) {
        float x = sp[(size_t)c * HW];
        sum += x; sq += x * x;
    }
    float mu   = sum * (1.0f / CDIM);
    float var  = fmaxf(sq * (1.0f / CDIM) - mu * mu, 0.0f);
    float rstd = rsqrtf(var + 1e-5f);
    float* xp = x2 + ((size_t)b * CDIM) * HW + p;
    for (int c = 0; c < CDIM; ++c) {
        float x = sp[(size_t)c * HW];
        xp[(size_t)c * HW] = (x - mu) * rstd * lnw[c] + lnb[c];
    }
}

// QKV GEMM: A = x2 in [B][C][HW] layout (K-major for us: As needs no transpose).
// C-tile 64(n) x 64(d), 256 threads, micro 4x4, K-chunks of 32.
__global__ __launch_bounds__(256) void k_gemm_qkv(const float* __restrict__ x2,
                                                  const float* __restrict__ W,
                                                  const float* __restrict__ bias,
                                                  float* __restrict__ qkv) {
    __shared__ float As[32][64];   // [k][n]
    __shared__ float Bs[32][68];   // [k][d], pad 68 keeps 16B row alignment
    int t  = threadIdx.x;
    int n0 = blockIdx.x * 64;
    int d0 = blockIdx.y * 64;
    int b  = n0 >> 12;
    int p0 = n0 & 4095;
    const float* Abase = x2 + ((size_t)b * CDIM) * HW + p0;

    int tn = t & 15, td = t >> 4;          // 16 x 16 thread grid
    float acc[4][4] = {{0.f}};

    for (int k0 = 0; k0 < CDIM; k0 += 32) {
        #pragma unroll
        for (int pass = 0; pass < 2; ++pass) {
            int cl = (t >> 4) + 16 * pass;             // 0..31 (K row)
            int n4 = (t & 15) * 4;
            float4 v = *(const float4*)(Abase + (size_t)(k0 + cl) * HW + n4);
            *(float4*)&As[cl][n4] = v;
        }
        #pragma unroll
        for (int pass = 0; pass < 2; ++pass) {
            int dl = (t >> 3) + 32 * pass;             // 0..63 (d row)
            int c4 = (t & 7) * 4;
            float4 v = *(const float4*)(W + (size_t)(d0 + dl) * CDIM + k0 + c4);
            Bs[c4 + 0][dl] = v.x; Bs[c4 + 1][dl] = v.y;
            Bs[c4 + 2][dl] = v.z; Bs[c4 + 3][dl] = v.w;
        }
        __syncthreads();
        #pragma unroll
        for (int kk = 0; kk < 32; ++kk) {
            float4 a  = *(const float4*)&As[kk][tn * 4];
            float4 b4 = *(const float4*)&Bs[kk][td * 4];
            acc[0][0] += a.x * b4.x; acc[0][1] += a.x * b4.y; acc[0][2] += a.x * b4.z; acc[0][3] += a.x * b4.w;
            acc[1][0] += a.y * b4.x; acc[1][1] += a.y * b4.y; acc[1][2] += a.y * b4.z; acc[1][3] += a.y * b4.w;
            acc[2][0] += a.z * b4.x; acc[2][1] += a.z * b4.y; acc[2][2] += a.z * b4.z; acc[2][3] += a.z * b4.w;
            acc[3][0] += a.w * b4.x; acc[3][1] += a.w * b4.y; acc[3][2] += a.w * b4.z; acc[3][3] += a.w * b4.w;
        }
        __syncthreads();
    }

    float b0 = bias[d0 + td * 4 + 0], b1 = bias[d0 + td * 4 + 1];
    float b2 = bias[d0 + td * 4 + 2], b3 = bias[d0 + td * 4 + 3];
    #pragma unroll
    for (int i = 0; i < 4; ++i) {
        float4 v = make_float4(acc[i][0] + b0, acc[i][1] + b1, acc[i][2] + b2, acc[i][3] + b3);
        *(float4*)(qkv + (size_t)(n0 + tn * 4 + i) * 768 + d0 + td * 4) = v;
    }
}

// One block (256 threads) per pixel. Thread = channel c; head = c>>5 (dh=32).
// Scores reduced over 32-lane groups with shfl_xor; softmax replicated per lane.
__global__ __launch_bounds__(256) void k_attn(const float* __restrict__ qkv,
                                              const float* __restrict__ pads,
                                              float* __restrict__ o) {
    int n = blockIdx.x;
    int c = threadIdx.x;
    int p = n & 4095;
    int h = p >> 6, w = p & 63;
    const float scale = 0.1767766952966369f;   // 1/sqrt(32)

    float q = qkv[(size_t)n * 768 + c];
    float sc[9];
    #pragma unroll
    for (int t9 = 0; t9 < 9; ++t9) {
        int dy = t9 / 3 - 1, dx = t9 % 3 - 1;
        int hh = h + dy, ww = w + dx;
        bool ok = ((unsigned)hh < 64u) && ((unsigned)ww < 64u);
        int nn = n + dy * 64 + dx;
        float k = ok ? qkv[(size_t)nn * 768 + 256 + c] : pads[c];
        float v = q * k;
        v += __shfl_xor(v, 1);
        v += __shfl_xor(v, 2);
        v += __shfl_xor(v, 4);
        v += __shfl_xor(v, 8);
        v += __shfl_xor(v, 16);
        sc[t9] = v * scale;
    }
    float m = sc[0];
    #pragma unroll
    for (int t9 = 1; t9 < 9; ++t9) m = fmaxf(m, sc[t9]);
    float s = 0.f;
    #pragma unroll
    for (int t9 = 0; t9 < 9; ++t9) { sc[t9] = __expf(sc[t9] - m); s += sc[t9]; }
    float inv = 1.0f / s;

    float oacc = 0.f;
    #pragma unroll
    for (int t9 = 0; t9 < 9; ++t9) {
        int dy = t9 / 3 - 1, dx = t9 % 3 - 1;
        int hh = h + dy, ww = w + dx;
        bool ok = ((unsigned)hh < 64u) && ((unsigned)ww < 64u);
        int nn = n + dy * 64 + dx;
        float v = ok ? qkv[(size_t)nn * 768 + 512 + c] : pads[256 + c];
        oacc += (sc[t9] * inv) * v;
    }
    o[(size_t)n * CDIM + c] = oacc;
}

// Out-proj GEMM + bias + residual + transpose back to [B][C][H][W].
__global__ __launch_bounds__(256) void k_outproj(const float* __restrict__ o,
                                                 const float* __restrict__ W,
                                                 const float* __restrict__ bias,
                                                 const float* __restrict__ src,
                                                 float* __restrict__ out) {
    __shared__ float As[32][68];   // [k][n]
    __shared__ float Bs[32][68];   // [k][d]
    __shared__ float Cs[64][65];   // [n][d], pad 65 -> conflict-free transpose read
    int t  = threadIdx.x;
    int n0 = blockIdx.x * 64;
    int d0 = blockIdx.y * 64;

    int tn = t & 15, td = t >> 4;
    float acc[4][4] = {{0.f}};

    for (int k0 = 0; k0 < CDIM; k0 += 32) {
        #pragma unroll
        for (int pass = 0; pass < 2; ++pass) {
            int rl = (t >> 3) + 32 * pass;             // 0..63
            int c4 = (t & 7) * 4;
            float4 va = *(const float4*)(o + (size_t)(n0 + rl) * CDIM + k0 + c4);
            As[c4 + 0][rl] = va.x; As[c4 + 1][rl] = va.y;
            As[c4 + 2][rl] = va.z; As[c4 + 3][rl] = va.w;
            float4 vb = *(const float4*)(W + (size_t)(d0 + rl) * CDIM + k0 + c4);
            Bs[c4 + 0][rl] = vb.x; Bs[c4 + 1][rl] = vb.y;
            Bs[c4 + 2][rl] = vb.z; Bs[c4 + 3][rl] = vb.w;
        }
        __syncthreads();
        #pragma unroll
        for (int kk = 0; kk < 32; ++kk) {
            float4 a  = *(const float4*)&As[kk][tn * 4];
            float4 b4 = *(const float4*)&Bs[kk][td * 4];
            acc[0][0] += a.x * b4.x; acc[0][1] += a.x * b4.y; acc[0][2] += a.x * b4.z; acc[0][3] += a.x * b4.w;
            acc[1][0] += a.y * b4.x; acc[1][1] += a.y * b4.y; acc[1][2] += a.y * b4.z; acc[1][3] += a.y * b4.w;
            acc[2][0] += a.z * b4.x; acc[2][1] += a.z * b4.y; acc[2][2] += a.z * b4.z; acc[2][3] += a.z * b4.w;
            acc[3][0] += a.w * b4.x; acc[3][1] += a.w * b4.y; acc[3][2] += a.w * b4.z; acc[3][3] += a.w * b4.w;
        }
        __syncthreads();
    }

    #pragma unroll
    for (int i = 0; i < 4; ++i)
        #pragma unroll
        for (int j = 0; j < 4; ++j)
            Cs[tn * 4 + i][td * 4 + j] = acc[i][j];
    __syncthreads();

    int b = n0 >> 12;
    int p0 = n0 & 4095;
    #pragma unroll
    for (int it = 0; it < 16; ++it) {
        int dl = (t >> 6) + 4 * it;    // 0..63 (output channel within tile)
        int nl = t & 63;               // pixel within tile
        float v = Cs[nl][dl] + bias[d0 + dl];
        size_t idx = ((size_t)(b * CDIM + d0 + dl)) * HW + p0 + nl;
        out[idx] = v + src[idx];
    }
}

extern "C" void kernel_launch(void* const* d_in, const int* in_sizes, int n_in,
                              void* d_out, int out_size, void* d_ws, size_t ws_size,
                              hipStream_t stream) {
    const float* src  = (const float*)d_in[0];
    const float* lnw  = (const float*)d_in[1];
    const float* lnb  = (const float*)d_in[2];
    const float* Wqkv = (const float*)d_in[3];
    const float* bqkv = (const float*)d_in[4];
    const float* Wout = (const float*)d_in[5];
    const float* bout = (const float*)d_in[6];
    float* out = (float*)d_out;

    float* ws   = (float*)d_ws;
    float* x2   = ws;                       // 4,194,304 floats (16.8 MB)
    float* qkv  = x2 + (size_t)NPIX * CDIM; // 12,582,912 floats (50.3 MB)
    float* oBuf = qkv + (size_t)NPIX * 768; // 4,194,304 floats (16.8 MB)
    float* pads = oBuf + (size_t)NPIX * CDIM; // 512 floats
    // total ~84 MB of d_ws

    k_pads<<<1, 512, 0, stream>>>(Wqkv, bqkv, lnb, pads);
    k_ln<<<NPIX / 256, 256, 0, stream>>>(src, lnw, lnb, x2);
    k_gemm_qkv<<<dim3(NPIX / 64, 768 / 64), 256, 0, stream>>>(x2, Wqkv, bqkv, qkv);
    k_attn<<<NPIX, 256, 0, stream>>>(qkv, pads, oBuf);
    k_outproj<<<dim3(NPIX / 64, CDIM / 64), 256, 0, stream>>>(oBuf, Wout, bout, src, out);
}

// Round 2
// 84.395 us; speedup vs baseline: 2.4173x; 2.4173x over previous
//
#include <hip/hip_runtime.h>
#include <math.h>

// CTransformer on MI355X, round 2: bf16 MFMA GEMMs + shuffle-free attention.
// B=4, C=256, H=W=64, NHEAD=8 (dh=32), 3x3 windows, only center token survives.
//
//   k_convert : Wqkv/Wout fp32 -> bf16
//   k_pads    : pad_k/pad_v for out-of-bounds neighbors (LN(0)=ln_b), fp32
//   k_ln_t    : LayerNorm + transpose [B][C][HW] -> x2bf[n][c] bf16
//   k_gemm_qkv: MFMA 16x16x32 bf16, 128x128 tile, qkvbf[n][768] = x2bf @ Wqkv^T + b
//   k_attn2   : thread = (pixel, head); serial dh=32 dot products, no shuffles
//   k_outproj : MFMA, operands swapped (M=d, N=pixel) so the fused
//               bias+residual store back to [B][C][H][W] is coalesced

#define NPIX 16384
#define HW   4096
#define CDIM 256

typedef short  bf16x8 __attribute__((ext_vector_type(8)));
typedef float  f32x4  __attribute__((ext_vector_type(4)));
typedef unsigned short u16x8 __attribute__((ext_vector_type(8)));

__device__ inline float bf2f(unsigned short u) {
    unsigned v = ((unsigned)u) << 16;
    return __builtin_bit_cast(float, v);
}
__device__ inline unsigned short f2bf(float f) {   // round-to-nearest-even
    unsigned u = __builtin_bit_cast(unsigned, f);
    u += 0x7FFFu + ((u >> 16) & 1u);
    return (unsigned short)(u >> 16);
}

__global__ __launch_bounds__(256) void k_convert(const float* __restrict__ Wqkv,
                                                 const float* __restrict__ Wout,
                                                 unsigned short* __restrict__ Wqkvbf,
                                                 unsigned short* __restrict__ Woutbf) {
    int i = blockIdx.x * 256 + threadIdx.x;           // 1024 blocks -> 262144
    if (i < 768 * 256) Wqkvbf[i] = f2bf(Wqkv[i]);
    else               Woutbf[i - 768 * 256] = f2bf(Wout[i - 768 * 256]);
}

__global__ void k_pads(const float* __restrict__ Wqkv, const float* __restrict__ bqkv,
                       const float* __restrict__ lnb, float* __restrict__ pads) {
    int d = threadIdx.x;            // 0..511 ; k rows 256..511, v rows 512..767
    int row = 256 + d;
    const float* wrow = Wqkv + (size_t)row * CDIM;
    float s = bqkv[row];
    for (int c = 0; c < CDIM; ++c) s += lnb[c] * wrow[c];
    pads[d] = s;
}

// LayerNorm + transpose: block handles 32 pixels x 256 channels.
__global__ __launch_bounds__(256) void k_ln_t(const float* __restrict__ src,
                                              const float* __restrict__ lnw,
                                              const float* __restrict__ lnb,
                                              unsigned short* __restrict__ x2bf) {
    __shared__ float tile[32][257];
    int t  = threadIdx.x;
    int n0 = blockIdx.x * 32;          // global pixel base (32 | 4096 -> one batch)
    int b  = n0 >> 12;
    int pp = n0 & 4095;
    const float* sbase = src + ((size_t)b * CDIM) * HW + pp;
    #pragma unroll
    for (int pass = 0; pass < 8; ++pass) {
        int c = (t >> 3) + 32 * pass;
        int f = t & 7;
        float4 v = *(const float4*)(sbase + (size_t)c * HW + f * 4);
        tile[f * 4 + 0][c] = v.x; tile[f * 4 + 1][c] = v.y;
        tile[f * 4 + 2][c] = v.z; tile[f * 4 + 3][c] = v.w;
    }
    __syncthreads();
    int p = t >> 3, q = t & 7;         // 8 threads per pixel
    float sum = 0.f, sq = 0.f;
    #pragma unroll
    for (int i = 0; i < 32; ++i) {
        float x = tile[p][q + 8 * i];
        sum += x; sq += x * x;
    }
    sum += __shfl_xor(sum, 1); sum += __shfl_xor(sum, 2); sum += __shfl_xor(sum, 4);
    sq  += __shfl_xor(sq, 1);  sq  += __shfl_xor(sq, 2);  sq  += __shfl_xor(sq, 4);
    float mu   = sum * (1.0f / CDIM);
    float var  = fmaxf(sq * (1.0f / CDIM) - mu * mu, 0.0f);
    float rstd = rsqrtf(var + 1e-5f);
    unsigned short* op = x2bf + (size_t)(n0 + p) * CDIM + q * 32;
    #pragma unroll
    for (int j0 = 0; j0 < 32; j0 += 8) {
        u16x8 o8;
        #pragma unroll
        for (int j = 0; j < 8; ++j) {
            int c = q * 32 + j0 + j;
            float x = (tile[p][c] - mu) * rstd * lnw[c] + lnb[c];
            o8[j] = f2bf(x);
        }
        *(u16x8*)(op + j0) = o8;
    }
}

// Stage a 128x64 bf16 tile (rows K-major, K-stride 256) into swizzled LDS.
__device__ inline void stage_tile(const unsigned short* __restrict__ g,
                                  unsigned short* s, int t) {
    #pragma unroll
    for (int it = 0; it < 4; ++it) {
        int chunk = t + 256 * it;                 // 0..1023 chunks of 16B
        int row = chunk >> 3;
        int c16 = chunk & 7;
        bf16x8 v = *(const bf16x8*)(g + row * 256 + c16 * 8);
        int off = (row * 128 + c16 * 16) ^ ((row & 7) << 4);
        *(bf16x8*)((char*)s + off) = v;
    }
}

// 128x128 MFMA GEMM core: acc[4][4] per wave (2x2 waves of 64x64 output).
#define GEMM_CORE(Ag, Bg)                                                        \
    int t = threadIdx.x, lane = t & 63, wid = t >> 6;                            \
    int wm = wid >> 1, wn = wid & 1;                                             \
    int lr = lane & 15, lg = lane >> 4;                                          \
    f32x4 acc[4][4] = {};                                                        \
    for (int k0 = 0; k0 < 256; k0 += 64) {                                       \
        if (k0) __syncthreads();                                                 \
        stage_tile(Ag + k0, As, t);                                              \
        stage_tile(Bg + k0, Bs, t);                                              \
        __syncthreads();                                                         \
        _Pragma("unroll")                                                        \
        for (int kk = 0; kk < 2; ++kk) {                                         \
            bf16x8 a[4], bb[4];                                                  \
            _Pragma("unroll")                                                    \
            for (int i = 0; i < 4; ++i) {                                        \
                int ar = wm * 64 + i * 16 + lr;                                  \
                a[i]  = *(bf16x8*)((char*)As + ((ar * 128 + kk * 64 + lg * 16)   \
                                                ^ ((ar & 7) << 4)));             \
                int br = wn * 64 + i * 16 + lr;                                  \
                bb[i] = *(bf16x8*)((char*)Bs + ((br * 128 + kk * 64 + lg * 16)   \
                                                ^ ((br & 7) << 4)));             \
            }                                                                    \
            _Pragma("unroll")                                                    \
            for (int i = 0; i < 4; ++i)                                          \
                _Pragma("unroll")                                                \
                for (int j = 0; j < 4; ++j)                                      \
                    acc[i][j] = __builtin_amdgcn_mfma_f32_16x16x32_bf16(         \
                        a[i], bb[j], acc[i][j], 0, 0, 0);                        \
        }                                                                        \
    }

// QKV: M=16384 pixels, N=768, K=256. Output bf16 [n][768] + bias.
__global__ __launch_bounds__(256) void k_gemm_qkv(const unsigned short* __restrict__ x2bf,
                                                  const unsigned short* __restrict__ Wbf,
                                                  const float* __restrict__ bias,
                                                  unsigned short* __restrict__ qkvbf) {
    __shared__ unsigned short As[128 * 64];
    __shared__ unsigned short Bs[128 * 64];
    int n0 = blockIdx.x * 128;
    int d0 = blockIdx.y * 128;
    const unsigned short* Ag = x2bf + (size_t)n0 * 256;
    const unsigned short* Bg = Wbf  + (size_t)d0 * 256;
    GEMM_CORE(Ag, Bg)
    #pragma unroll
    for (int j = 0; j < 4; ++j) {
        int colg = d0 + wn * 64 + j * 16 + lr;
        float bj = bias[colg];
        #pragma unroll
        for (int i = 0; i < 4; ++i) {
            #pragma unroll
            for (int r = 0; r < 4; ++r) {
                int rowg = n0 + wm * 64 + i * 16 + lg * 4 + r;
                qkvbf[(size_t)rowg * 768 + colg] = f2bf(acc[i][j][r] + bj);
            }
        }
    }
}

// Attention: thread = (pixel, head). q scaled in regs; serial dh=32 dots.
__global__ __launch_bounds__(256) void k_attn2(const unsigned short* __restrict__ qkvbf,
                                               const float* __restrict__ pads,
                                               unsigned short* __restrict__ obf) {
    int t = blockIdx.x * 256 + threadIdx.x;   // 131072 threads
    int n = t >> 3, h = t & 7;
    int p = n & 4095, hh0 = p >> 6, ww0 = p & 63;
    const float scale = 0.1767766952966369f;  // 1/sqrt(32)

    float qv[32];
    const unsigned short* qp = qkvbf + (size_t)n * 768 + h * 32;
    #pragma unroll
    for (int c8 = 0; c8 < 4; ++c8) {
        bf16x8 v = *(const bf16x8*)(qp + c8 * 8);
        #pragma unroll
        for (int j = 0; j < 8; ++j) qv[c8 * 8 + j] = bf2f((unsigned short)v[j]) * scale;
    }

    float sc[9];
    #pragma unroll
    for (int t9 = 0; t9 < 9; ++t9) {
        int dy = t9 / 3 - 1, dx = t9 % 3 - 1;
        int hh = hh0 + dy, ww = ww0 + dx;
        bool ok = ((unsigned)hh < 64u) && ((unsigned)ww < 64u);
        float a = 0.f;
        if (ok) {
            const unsigned short* kp = qkvbf + (size_t)(n + dy * 64 + dx) * 768 + 256 + h * 32;
            #pragma unroll
            for (int c8 = 0; c8 < 4; ++c8) {
                bf16x8 v = *(const bf16x8*)(kp + c8 * 8);
                #pragma unroll
                for (int j = 0; j < 8; ++j) a += qv[c8 * 8 + j] * bf2f((unsigned short)v[j]);
            }
        } else {
            const float* pk = pads + h * 32;
            #pragma unroll
            for (int j = 0; j < 32; ++j) a += qv[j] * pk[j];
        }
        sc[t9] = a;
    }
    float m = sc[0];
    #pragma unroll
    for (int t9 = 1; t9 < 9; ++t9) m = fmaxf(m, sc[t9]);
    float s = 0.f;
    #pragma unroll
    for (int t9 = 0; t9 < 9; ++t9) { sc[t9] = __expf(sc[t9] - m); s += sc[t9]; }
    float inv = 1.0f / s;

    float ov[32];
    #pragma unroll
    for (int j = 0; j < 32; ++j) ov[j] = 0.f;
    #pragma unroll
    for (int t9 = 0; t9 < 9; ++t9) {
        int dy = t9 / 3 - 1, dx = t9 % 3 - 1;
        int hh = hh0 + dy, ww = ww0 + dx;
        bool ok = ((unsigned)hh < 64u) && ((unsigned)ww < 64u);
        float w = sc[t9] * inv;
        if (ok) {
            const unsigned short* vp = qkvbf + (size_t)(n + dy * 64 + dx) * 768 + 512 + h * 32;
            #pragma unroll
            for (int c8 = 0; c8 < 4; ++c8) {
                bf16x8 v = *(const bf16x8*)(vp + c8 * 8);
                #pragma unroll
                for (int j = 0; j < 8; ++j) ov[c8 * 8 + j] += w * bf2f((unsigned short)v[j]);
            }
        } else {
            const float* pv = pads + 256 + h * 32;
            #pragma unroll
            for (int j = 0; j < 32; ++j) ov[j] += w * pv[j];
        }
    }
    unsigned short* op = obf + (size_t)n * CDIM + h * 32;
    #pragma unroll
    for (int c8 = 0; c8 < 4; ++c8) {
        u16x8 o8;
        #pragma unroll
        for (int j = 0; j < 8; ++j) o8[j] = f2bf(ov[c8 * 8 + j]);
        *(u16x8*)(op + c8 * 8) = o8;
    }
}

// Out-proj, swapped operands: M = channel (256), N = pixel (16384), K = 256.
// Epilogue: + bias + residual, coalesced store to [B][C][H][W] fp32.
__global__ __launch_bounds__(256) void k_outproj(const unsigned short* __restrict__ obf,
                                                 const unsigned short* __restrict__ Wbf,
                                                 const float* __restrict__ bias,
                                                 const float* __restrict__ src,
                                                 float* __restrict__ out) {
    __shared__ unsigned short As[128 * 64];
    __shared__ unsigned short Bs[128 * 64];
    int n0 = blockIdx.x * 128;   // pixel tile
    int d0 = blockIdx.y * 128;   // channel tile
    const unsigned short* Ag = Wbf + (size_t)d0 * 256;   // A rows = channels
    const unsigned short* Bg = obf + (size_t)n0 * 256;   // B rows = pixels
    GEMM_CORE(Ag, Bg)
    int b = n0 >> 12;
    #pragma unroll
    for (int i = 0; i < 4; ++i) {
        #pragma unroll
        for (int r = 0; r < 4; ++r) {
            int dg = d0 + wm * 64 + i * 16 + lg * 4 + r;
            float bd = bias[dg];
            #pragma unroll
            for (int j = 0; j < 4; ++j) {
                int ng = n0 + wn * 64 + j * 16 + lr;
                size_t idx = ((size_t)(b * CDIM + dg)) * HW + (ng & 4095);
                out[idx] = acc[i][j][r] + bd + src[idx];
            }
        }
    }
}

extern "C" void kernel_launch(void* const* d_in, const int* in_sizes, int n_in,
                              void* d_out, int out_size, void* d_ws, size_t ws_size,
                              hipStream_t stream) {
    const float* src  = (const float*)d_in[0];
    const float* lnw  = (const float*)d_in[1];
    const float* lnb  = (const float*)d_in[2];
    const float* Wqkv = (const float*)d_in[3];
    const float* bqkv = (const float*)d_in[4];
    const float* Wout = (const float*)d_in[5];
    const float* bout = (const float*)d_in[6];
    float* out = (float*)d_out;

    unsigned short* x2bf   = (unsigned short*)d_ws;               // 16384*256
    unsigned short* qkvbf  = x2bf  + (size_t)NPIX * CDIM;         // 16384*768
    unsigned short* obf    = qkvbf + (size_t)NPIX * 768;          // 16384*256
    unsigned short* Wqkvbf = obf   + (size_t)NPIX * CDIM;         // 768*256
    unsigned short* Woutbf = Wqkvbf + 768 * 256;                  // 256*256
    float* pads = (float*)(Woutbf + 256 * 256);                   // 512 floats
    // total ~42.5 MB of d_ws

    k_convert<<<1024, 256, 0, stream>>>(Wqkv, Wout, Wqkvbf, Woutbf);
    k_pads<<<1, 512, 0, stream>>>(Wqkv, bqkv, lnb, pads);
    k_ln_t<<<NPIX / 32, 256, 0, stream>>>(src, lnw, lnb, x2bf);
    k_gemm_qkv<<<dim3(NPIX / 128, 768 / 128), 256, 0, stream>>>(x2bf, Wqkvbf, bqkv, qkvbf);
    k_attn2<<<(NPIX * 8) / 256, 256, 0, stream>>>(qkvbf, pads, obf);
    k_outproj<<<dim3(NPIX / 128, CDIM / 128), 256, 0, stream>>>(obf, Woutbf, bout, src, out);
}

// Round 3
// 79.958 us; speedup vs baseline: 2.5514x; 1.0555x over previous
//
#include <hip/hip_runtime.h>
#include <math.h>

// CTransformer on MI355X, round 3: m97-style GEMMs (global_load_lds + linear LDS),
// XCD-swizzled QKV grid, fused prep kernel.
// B=4, C=256, H=W=64, NHEAD=8 (dh=32), 3x3 windows, only center token survives.
//
//   k_prep    : Wqkv/Wout fp32->bf16 + pad_k/pad_v vectors (LN(0)=ln_b)
//   k_ln_t    : LayerNorm + transpose [B][C][HW] -> x2bf[n][c] bf16
//   k_gemm_qkv: MFMA 16x16x32 bf16, 128x128 tile, global_load_lds staging,
//               XCD-swizzled 1-D grid (d-tile minor -> A-tile L2 reuse per XCD)
//   k_attn2   : thread = (pixel, head); serial dh=32 dot products
//   k_outproj : same GEMM core, operands swapped (M=channel, N=pixel) so the
//               fused bias+residual store back to [B][C][H][W] fp32 is coalesced

#define NPIX 16384
#define HW   4096
#define CDIM 256

typedef short  bf16x8 __attribute__((ext_vector_type(8)));
typedef float  f32x4  __attribute__((ext_vector_type(4)));
typedef unsigned short u16x8 __attribute__((ext_vector_type(8)));

__device__ inline float bf2f(unsigned short u) {
    unsigned v = ((unsigned)u) << 16;
    return __builtin_bit_cast(float, v);
}
__device__ inline unsigned short f2bf(float f) {   // round-to-nearest-even
    unsigned u = __builtin_bit_cast(unsigned, f);
    u += 0x7FFFu + ((u >> 16) & 1u);
    return (unsigned short)(u >> 16);
}

// ---- prep: weight conversions + pad vectors, one launch -------------------
__global__ __launch_bounds__(256) void k_prep(const float* __restrict__ Wqkv,
                                              const float* __restrict__ Wout,
                                              const float* __restrict__ bqkv,
                                              const float* __restrict__ lnb,
                                              unsigned short* __restrict__ Wqkvbf,
                                              unsigned short* __restrict__ Woutbf,
                                              float* __restrict__ pads) {
    int bid = blockIdx.x, t = threadIdx.x;
    if (bid < 768) {                       // Wqkv: 196608 elements
        int i = bid * 256 + t;
        Wqkvbf[i] = f2bf(Wqkv[i]);
    } else if (bid < 1024) {               // Wout: 65536 elements
        int i = (bid - 768) * 256 + t;
        Woutbf[i] = f2bf(Wout[i]);
    } else {                               // pads: 512 dot products
        int d = (bid - 1024) * 256 + t;    // 0..511; k rows 256..511, v rows 512..767
        int row = 256 + d;
        const float* wrow = Wqkv + (size_t)row * CDIM;
        float s = bqkv[row];
        for (int c = 0; c < CDIM; ++c) s += lnb[c] * wrow[c];
        pads[d] = s;
    }
}

// ---- LayerNorm + transpose: block = 32 pixels x 256 channels --------------
__global__ __launch_bounds__(256) void k_ln_t(const float* __restrict__ src,
                                              const float* __restrict__ lnw,
                                              const float* __restrict__ lnb,
                                              unsigned short* __restrict__ x2bf) {
    __shared__ float tile[32][257];
    int t  = threadIdx.x;
    int n0 = blockIdx.x * 32;
    int b  = n0 >> 12;
    int pp = n0 & 4095;
    const float* sbase = src + ((size_t)b * CDIM) * HW + pp;
    #pragma unroll
    for (int pass = 0; pass < 8; ++pass) {
        int c = (t >> 3) + 32 * pass;
        int f = t & 7;
        float4 v = *(const float4*)(sbase + (size_t)c * HW + f * 4);
        tile[f * 4 + 0][c] = v.x; tile[f * 4 + 1][c] = v.y;
        tile[f * 4 + 2][c] = v.z; tile[f * 4 + 3][c] = v.w;
    }
    __syncthreads();
    int p = t >> 3, q = t & 7;             // 8 threads per pixel
    float sum = 0.f, sq = 0.f;
    #pragma unroll
    for (int i = 0; i < 32; ++i) {
        float x = tile[p][q + 8 * i];
        sum += x; sq += x * x;
    }
    sum += __shfl_xor(sum, 1); sum += __shfl_xor(sum, 2); sum += __shfl_xor(sum, 4);
    sq  += __shfl_xor(sq, 1);  sq  += __shfl_xor(sq, 2);  sq  += __shfl_xor(sq, 4);
    float mu   = sum * (1.0f / CDIM);
    float var  = fmaxf(sq * (1.0f / CDIM) - mu * mu, 0.0f);
    float rstd = rsqrtf(var + 1e-5f);
    unsigned short* op = x2bf + (size_t)(n0 + p) * CDIM + q * 32;
    #pragma unroll
    for (int j0 = 0; j0 < 32; j0 += 8) {
        u16x8 o8;
        #pragma unroll
        for (int j = 0; j < 8; ++j) {
            int c = q * 32 + j0 + j;
            float x = (tile[p][c] - mu) * rstd * lnw[c] + lnb[c];
            o8[j] = f2bf(x);
        }
        *(u16x8*)(op + j0) = o8;
    }
}

// ---- global_load_lds staging: 128 rows x 64 k bf16, row stride 256 --------
// LDS layout linear [128][64] u16; dest = wave-uniform base + lane*16.
__device__ inline void stage64(const unsigned short* __restrict__ g,
                               unsigned short* lds, int t) {
    int lane = t & 63;
    int wv   = t >> 6;
    #pragma unroll
    for (int it = 0; it < 4; ++it) {
        int rbase = wv * 32 + it * 8;                    // wave-uniform
        const unsigned short* src = g + (size_t)(rbase + (lane >> 3)) * 256 + (lane & 7) * 8;
        __builtin_amdgcn_global_load_lds(
            (const __attribute__((address_space(1))) void*)src,
            (__attribute__((address_space(3))) void*)(lds + rbase * 64),
            16, 0, 0);
    }
}

// 128x128 MFMA GEMM core: 4 waves (2x2), acc[4][4] f32x4 per lane.
#define GEMM_CORE(Ag, Bg)                                                        \
    int t = threadIdx.x, lane = t & 63, wid = t >> 6;                            \
    int wm = wid >> 1, wn = wid & 1;                                             \
    int lr = lane & 15, lg = lane >> 4;                                          \
    f32x4 acc[4][4] = {};                                                        \
    for (int k0 = 0; k0 < 256; k0 += 64) {                                       \
        if (k0) __syncthreads();                                                 \
        stage64(Ag + k0, As, t);                                                 \
        stage64(Bg + k0, Bs, t);                                                 \
        __syncthreads();                                                         \
        _Pragma("unroll")                                                        \
        for (int kk = 0; kk < 2; ++kk) {                                         \
            bf16x8 a[4], bb[4];                                                  \
            _Pragma("unroll")                                                    \
            for (int i = 0; i < 4; ++i) {                                        \
                a[i]  = *(bf16x8*)(As + (wm * 64 + i * 16 + lr) * 64 + kk * 32 + lg * 8); \
                bb[i] = *(bf16x8*)(Bs + (wn * 64 + i * 16 + lr) * 64 + kk * 32 + lg * 8); \
            }                                                                    \
            _Pragma("unroll")                                                    \
            for (int i = 0; i < 4; ++i)                                          \
                _Pragma("unroll")                                                \
                for (int j = 0; j < 4; ++j)                                      \
                    acc[i][j] = __builtin_amdgcn_mfma_f32_16x16x32_bf16(         \
                        a[i], bb[j], acc[i][j], 0, 0, 0);                        \
        }                                                                        \
    }

// ---- QKV GEMM: M=16384 pixels, N=768, K=256; XCD-swizzled 1-D grid --------
__global__ __launch_bounds__(256) void k_gemm_qkv(const unsigned short* __restrict__ x2bf,
                                                  const unsigned short* __restrict__ Wbf,
                                                  const float* __restrict__ bias,
                                                  unsigned short* __restrict__ qkvbf) {
    __shared__ unsigned short As[128 * 64];
    __shared__ unsigned short Bs[128 * 64];
    // 768 blocks = 8 XCDs x 96. Logical order: d-tile minor (6 per n-tile) so each
    // XCD's contiguous chunk reuses 16 A-tiles + all of W from its private L2.
    int bid = blockIdx.x;
    int L = (bid & 7) * 96 + (bid >> 3);
    int n0 = (L / 6) * 128;
    int d0 = (L % 6) * 128;
    const unsigned short* Ag = x2bf + (size_t)n0 * 256;
    const unsigned short* Bg = Wbf  + (size_t)d0 * 256;
    GEMM_CORE(Ag, Bg)
    #pragma unroll
    for (int j = 0; j < 4; ++j) {
        int colg = d0 + wn * 64 + j * 16 + lr;
        float bj = bias[colg];
        #pragma unroll
        for (int i = 0; i < 4; ++i) {
            #pragma unroll
            for (int r = 0; r < 4; ++r) {
                int rowg = n0 + wm * 64 + i * 16 + lg * 4 + r;
                qkvbf[(size_t)rowg * 768 + colg] = f2bf(acc[i][j][r] + bj);
            }
        }
    }
}

// ---- Attention: thread = (pixel, head); serial dh=32 dots -----------------
__global__ __launch_bounds__(256) void k_attn2(const unsigned short* __restrict__ qkvbf,
                                               const float* __restrict__ pads,
                                               unsigned short* __restrict__ obf) {
    int t = blockIdx.x * 256 + threadIdx.x;   // 131072 threads
    int n = t >> 3, h = t & 7;
    int p = n & 4095, hh0 = p >> 6, ww0 = p & 63;
    const float scale = 0.1767766952966369f;  // 1/sqrt(32)

    float qv[32];
    const unsigned short* qp = qkvbf + (size_t)n * 768 + h * 32;
    #pragma unroll
    for (int c8 = 0; c8 < 4; ++c8) {
        bf16x8 v = *(const bf16x8*)(qp + c8 * 8);
        #pragma unroll
        for (int j = 0; j < 8; ++j) qv[c8 * 8 + j] = bf2f((unsigned short)v[j]) * scale;
    }

    float sc[9];
    #pragma unroll
    for (int t9 = 0; t9 < 9; ++t9) {
        int dy = t9 / 3 - 1, dx = t9 % 3 - 1;
        int hh = hh0 + dy, ww = ww0 + dx;
        bool ok = ((unsigned)hh < 64u) && ((unsigned)ww < 64u);
        float a = 0.f;
        if (ok) {
            const unsigned short* kp = qkvbf + (size_t)(n + dy * 64 + dx) * 768 + 256 + h * 32;
            #pragma unroll
            for (int c8 = 0; c8 < 4; ++c8) {
                bf16x8 v = *(const bf16x8*)(kp + c8 * 8);
                #pragma unroll
                for (int j = 0; j < 8; ++j) a += qv[c8 * 8 + j] * bf2f((unsigned short)v[j]);
            }
        } else {
            const float* pk = pads + h * 32;
            #pragma unroll
            for (int j = 0; j < 32; ++j) a += qv[j] * pk[j];
        }
        sc[t9] = a;
    }
    float m = sc[0];
    #pragma unroll
    for (int t9 = 1; t9 < 9; ++t9) m = fmaxf(m, sc[t9]);
    float s = 0.f;
    #pragma unroll
    for (int t9 = 0; t9 < 9; ++t9) { sc[t9] = __expf(sc[t9] - m); s += sc[t9]; }
    float inv = 1.0f / s;

    float ov[32];
    #pragma unroll
    for (int j = 0; j < 32; ++j) ov[j] = 0.f;
    #pragma unroll
    for (int t9 = 0; t9 < 9; ++t9) {
        int dy = t9 / 3 - 1, dx = t9 % 3 - 1;
        int hh = hh0 + dy, ww = ww0 + dx;
        bool ok = ((unsigned)hh < 64u) && ((unsigned)ww < 64u);
        float w = sc[t9] * inv;
        if (ok) {
            const unsigned short* vp = qkvbf + (size_t)(n + dy * 64 + dx) * 768 + 512 + h * 32;
            #pragma unroll
            for (int c8 = 0; c8 < 4; ++c8) {
                bf16x8 v = *(const bf16x8*)(vp + c8 * 8);
                #pragma unroll
                for (int j = 0; j < 8; ++j) ov[c8 * 8 + j] += w * bf2f((unsigned short)v[j]);
            }
        } else {
            const float* pv = pads + 256 + h * 32;
            #pragma unroll
            for (int j = 0; j < 32; ++j) ov[j] += w * pv[j];
        }
    }
    unsigned short* op = obf + (size_t)n * CDIM + h * 32;
    #pragma unroll
    for (int c8 = 0; c8 < 4; ++c8) {
        u16x8 o8;
        #pragma unroll
        for (int j = 0; j < 8; ++j) o8[j] = f2bf(ov[c8 * 8 + j]);
        *(u16x8*)(op + c8 * 8) = o8;
    }
}

// ---- Out-proj: M=channel(256), N=pixel(16384), K=256; fused residual ------
__global__ __launch_bounds__(256) void k_outproj(const unsigned short* __restrict__ obf,
                                                 const unsigned short* __restrict__ Wbf,
                                                 const float* __restrict__ bias,
                                                 const float* __restrict__ src,
                                                 float* __restrict__ out) {
    __shared__ unsigned short As[128 * 64];
    __shared__ unsigned short Bs[128 * 64];
    int n0 = blockIdx.x * 128;   // pixel tile
    int d0 = blockIdx.y * 128;   // channel tile
    const unsigned short* Ag = Wbf + (size_t)d0 * 256;   // A rows = channels
    const unsigned short* Bg = obf + (size_t)n0 * 256;   // B rows = pixels
    GEMM_CORE(Ag, Bg)
    int b = n0 >> 12;
    #pragma unroll
    for (int i = 0; i < 4; ++i) {
        #pragma unroll
        for (int r = 0; r < 4; ++r) {
            int dg = d0 + wm * 64 + i * 16 + lg * 4 + r;
            float bd = bias[dg];
            #pragma unroll
            for (int j = 0; j < 4; ++j) {
                int ng = n0 + wn * 64 + j * 16 + lr;
                size_t idx = ((size_t)(b * CDIM + dg)) * HW + (ng & 4095);
                out[idx] = acc[i][j][r] + bd + src[idx];
            }
        }
    }
}

extern "C" void kernel_launch(void* const* d_in, const int* in_sizes, int n_in,
                              void* d_out, int out_size, void* d_ws, size_t ws_size,
                              hipStream_t stream) {
    const float* src  = (const float*)d_in[0];
    const float* lnw  = (const float*)d_in[1];
    const float* lnb  = (const float*)d_in[2];
    const float* Wqkv = (const float*)d_in[3];
    const float* bqkv = (const float*)d_in[4];
    const float* Wout = (const float*)d_in[5];
    const float* bout = (const float*)d_in[6];
    float* out = (float*)d_out;

    unsigned short* x2bf   = (unsigned short*)d_ws;               // 16384*256
    unsigned short* qkvbf  = x2bf  + (size_t)NPIX * CDIM;         // 16384*768
    unsigned short* obf    = qkvbf + (size_t)NPIX * 768;          // 16384*256
    unsigned short* Wqkvbf = obf   + (size_t)NPIX * CDIM;         // 768*256
    unsigned short* Woutbf = Wqkvbf + 768 * 256;                  // 256*256
    float* pads = (float*)(Woutbf + 256 * 256);                   // 512 floats
    // total ~42.5 MB of d_ws

    k_prep<<<1026, 256, 0, stream>>>(Wqkv, Wout, bqkv, lnb, Wqkvbf, Woutbf, pads);
    k_ln_t<<<NPIX / 32, 256, 0, stream>>>(src, lnw, lnb, x2bf);
    k_gemm_qkv<<<768, 256, 0, stream>>>(x2bf, Wqkvbf, bqkv, qkvbf);
    k_attn2<<<(NPIX * 8) / 256, 256, 0, stream>>>(qkvbf, pads, obf);
    k_outproj<<<dim3(NPIX / 128, CDIM / 128), 256, 0, stream>>>(obf, Woutbf, bout, src, out);
}

// Round 4
// 64.442 us; speedup vs baseline: 3.1657x; 1.2408x over previous
//
#include <hip/hip_runtime.h>
#include <math.h>

// CTransformer on MI355X, round 4:
//   k_prep     : Wqkv/Wout fp32->bf16 + pad_k/pad_v vectors (LN(0)=ln_b)
//   k_ln_t     : LayerNorm + transpose [B][C][HW] -> x2bf[n][c] bf16
//   k_gemm_qkv : MFMA 128x128 tile, global_load_lds staging, XCD-swizzled grid,
//                NEW: LDS-transposed epilogue -> coalesced bf16x8 stores
//   k_attn_proj: FUSED attention + out-proj. Block = 64 pixels (one image row)
//                x 256 output channels, 512 threads. Attention output lives in
//                LDS (no obf round-trip); fused bias+residual store to fp32.

#define NPIX 16384
#define HW   4096
#define CDIM 256

typedef short  bf16x8 __attribute__((ext_vector_type(8)));
typedef float  f32x4  __attribute__((ext_vector_type(4)));
typedef unsigned short u16x8 __attribute__((ext_vector_type(8)));

__device__ inline float bf2f(unsigned short u) {
    unsigned v = ((unsigned)u) << 16;
    return __builtin_bit_cast(float, v);
}
__device__ inline unsigned short f2bf(float f) {   // round-to-nearest-even
    unsigned u = __builtin_bit_cast(unsigned, f);
    u += 0x7FFFu + ((u >> 16) & 1u);
    return (unsigned short)(u >> 16);
}

// ---- prep: weight conversions + pad vectors --------------------------------
__global__ __launch_bounds__(256) void k_prep(const float* __restrict__ Wqkv,
                                              const float* __restrict__ Wout,
                                              const float* __restrict__ bqkv,
                                              const float* __restrict__ lnb,
                                              unsigned short* __restrict__ Wqkvbf,
                                              unsigned short* __restrict__ Woutbf,
                                              float* __restrict__ pads) {
    int bid = blockIdx.x, t = threadIdx.x;
    if (bid < 768) {
        int i = bid * 256 + t;
        Wqkvbf[i] = f2bf(Wqkv[i]);
    } else if (bid < 1024) {
        int i = (bid - 768) * 256 + t;
        Woutbf[i] = f2bf(Wout[i]);
    } else {
        int d = (bid - 1024) * 256 + t;    // 0..511; k rows 256..511, v rows 512..767
        int row = 256 + d;
        const float* wrow = Wqkv + (size_t)row * CDIM;
        float s = bqkv[row];
        for (int c = 0; c < CDIM; ++c) s += lnb[c] * wrow[c];
        pads[d] = s;
    }
}

// ---- LayerNorm + transpose: block = 32 pixels x 256 channels ---------------
__global__ __launch_bounds__(256) void k_ln_t(const float* __restrict__ src,
                                              const float* __restrict__ lnw,
                                              const float* __restrict__ lnb,
                                              unsigned short* __restrict__ x2bf) {
    __shared__ float tile[32][257];
    int t  = threadIdx.x;
    int n0 = blockIdx.x * 32;
    int b  = n0 >> 12;
    int pp = n0 & 4095;
    const float* sbase = src + ((size_t)b * CDIM) * HW + pp;
    #pragma unroll
    for (int pass = 0; pass < 8; ++pass) {
        int c = (t >> 3) + 32 * pass;
        int f = t & 7;
        float4 v = *(const float4*)(sbase + (size_t)c * HW + f * 4);
        tile[f * 4 + 0][c] = v.x; tile[f * 4 + 1][c] = v.y;
        tile[f * 4 + 2][c] = v.z; tile[f * 4 + 3][c] = v.w;
    }
    __syncthreads();
    int p = t >> 3, q = t & 7;             // 8 threads per pixel
    float sum = 0.f, sq = 0.f;
    #pragma unroll
    for (int i = 0; i < 32; ++i) {
        float x = tile[p][q + 8 * i];
        sum += x; sq += x * x;
    }
    sum += __shfl_xor(sum, 1); sum += __shfl_xor(sum, 2); sum += __shfl_xor(sum, 4);
    sq  += __shfl_xor(sq, 1);  sq  += __shfl_xor(sq, 2);  sq  += __shfl_xor(sq, 4);
    float mu   = sum * (1.0f / CDIM);
    float var  = fmaxf(sq * (1.0f / CDIM) - mu * mu, 0.0f);
    float rstd = rsqrtf(var + 1e-5f);
    unsigned short* op = x2bf + (size_t)(n0 + p) * CDIM + q * 32;
    #pragma unroll
    for (int j0 = 0; j0 < 32; j0 += 8) {
        u16x8 o8;
        #pragma unroll
        for (int j = 0; j < 8; ++j) {
            int c = q * 32 + j0 + j;
            float x = (tile[p][c] - mu) * rstd * lnw[c] + lnb[c];
            o8[j] = f2bf(x);
        }
        *(u16x8*)(op + j0) = o8;
    }
}

// ---- global_load_lds staging: NW*32 rows x 64 k bf16, row stride 256 -------
// Works for 4 waves (128 rows) and 8 waves (256 rows): rows = wv*32 + it*8 + lane>>3.
__device__ inline void stage64(const unsigned short* __restrict__ g,
                               unsigned short* lds, int t) {
    int lane = t & 63;
    int wv   = t >> 6;
    #pragma unroll
    for (int it = 0; it < 4; ++it) {
        int rbase = wv * 32 + it * 8;                    // wave-uniform
        const unsigned short* src = g + (size_t)(rbase + (lane >> 3)) * 256 + (lane & 7) * 8;
        __builtin_amdgcn_global_load_lds(
            (const __attribute__((address_space(1))) void*)src,
            (__attribute__((address_space(3))) void*)(lds + rbase * 64),
            16, 0, 0);
    }
}

// ---- QKV GEMM: M=16384 pixels, N=768, K=256; XCD-swizzled; LDS-T epilogue --
__global__ __launch_bounds__(256) void k_gemm_qkv(const unsigned short* __restrict__ x2bf,
                                                  const unsigned short* __restrict__ Wbf,
                                                  const float* __restrict__ bias,
                                                  unsigned short* __restrict__ qkvbf) {
    __shared__ unsigned short smem[128 * 136];   // As(8K u16) + Bs(8K u16), reused as [128][136]
    unsigned short* As = smem;
    unsigned short* Bs = smem + 128 * 64;
    int bid = blockIdx.x;
    int L = (bid & 7) * 96 + (bid >> 3);         // 768 = 8 XCDs x 96, bijective
    int n0 = (L / 6) * 128;
    int d0 = (L % 6) * 128;
    const unsigned short* Ag = x2bf + (size_t)n0 * 256;
    const unsigned short* Bg = Wbf  + (size_t)d0 * 256;

    int t = threadIdx.x, lane = t & 63, wid = t >> 6;
    int wm = wid >> 1, wn = wid & 1;
    int lr = lane & 15, lg = lane >> 4;
    f32x4 acc[4][4] = {};
    for (int k0 = 0; k0 < 256; k0 += 64) {
        if (k0) __syncthreads();
        stage64(Ag + k0, As, t);
        stage64(Bg + k0, Bs, t);
        __syncthreads();
        #pragma unroll
        for (int kk = 0; kk < 2; ++kk) {
            bf16x8 a[4], bb[4];
            #pragma unroll
            for (int i = 0; i < 4; ++i) {
                a[i]  = *(bf16x8*)(As + (wm * 64 + i * 16 + lr) * 64 + kk * 32 + lg * 8);
                bb[i] = *(bf16x8*)(Bs + (wn * 64 + i * 16 + lr) * 64 + kk * 32 + lg * 8);
            }
            #pragma unroll
            for (int i = 0; i < 4; ++i)
                #pragma unroll
                for (int j = 0; j < 4; ++j)
                    acc[i][j] = __builtin_amdgcn_mfma_f32_16x16x32_bf16(
                        a[i], bb[j], acc[i][j], 0, 0, 0);
        }
    }
    // transpose epilogue: acc -> smem[pix][d] bf16 (+bias), then coalesced stores
    __syncthreads();
    #pragma unroll
    for (int j = 0; j < 4; ++j) {
        float bj = bias[d0 + wn * 64 + j * 16 + lr];
        #pragma unroll
        for (int i = 0; i < 4; ++i)
            #pragma unroll
            for (int r = 0; r < 4; ++r)
                smem[(wm * 64 + i * 16 + lg * 4 + r) * 136 + wn * 64 + j * 16 + lr] =
                    f2bf(acc[i][j][r] + bj);
    }
    __syncthreads();
    #pragma unroll
    for (int it = 0; it < 8; ++it) {
        int row = (t >> 4) + 16 * it;
        int c8  = t & 15;
        bf16x8 v = *(bf16x8*)(smem + row * 136 + c8 * 8);
        *(bf16x8*)(qkvbf + (size_t)(n0 + row) * 768 + d0 + c8 * 8) = v;
    }
}

// ---- FUSED attention + out-proj --------------------------------------------
// Block = 64 pixels (one image row) x 256 out channels; 512 threads (8 waves).
// Phase 1: thread = (pixel, head) -> attention output bf16 into Bt[64][264].
// Phase 2: GEMM M=256(ch) x N=64(pix) x K=256; A=Wout via global_load_lds,
//          B-fragments straight from Bt. Fused bias + residual fp32 store.
__global__ __launch_bounds__(512) void k_attn_proj(const unsigned short* __restrict__ qkvbf,
                                                   const float* __restrict__ pads,
                                                   const unsigned short* __restrict__ Wbf,
                                                   const float* __restrict__ bias,
                                                   const float* __restrict__ src,
                                                   float* __restrict__ out) {
    __shared__ unsigned short Bt[64 * 264];   // attention out [pix][c], pad 264
    __shared__ unsigned short As[256 * 64];   // W tile [ch][k-chunk]
    int t  = threadIdx.x;
    int n0 = blockIdx.x * 64;
    int b  = n0 >> 12;
    int p0 = n0 & 4095;

    // ---- phase 1: attention for 64 pixels ----
    {
        int pix = t >> 3, h = t & 7;
        int n = n0 + pix;
        int p = n & 4095, hh0 = p >> 6, ww0 = p & 63;
        const float scale = 0.1767766952966369f;  // 1/sqrt(32)

        float qv[32];
        const unsigned short* qp = qkvbf + (size_t)n * 768 + h * 32;
        #pragma unroll
        for (int c8 = 0; c8 < 4; ++c8) {
            bf16x8 v = *(const bf16x8*)(qp + c8 * 8);
            #pragma unroll
            for (int j = 0; j < 8; ++j) qv[c8 * 8 + j] = bf2f((unsigned short)v[j]) * scale;
        }
        float sc[9];
        #pragma unroll
        for (int t9 = 0; t9 < 9; ++t9) {
            int dy = t9 / 3 - 1, dx = t9 % 3 - 1;
            int hh = hh0 + dy, ww = ww0 + dx;
            bool ok = ((unsigned)hh < 64u) && ((unsigned)ww < 64u);
            float a = 0.f;
            if (ok) {
                const unsigned short* kp = qkvbf + (size_t)(n + dy * 64 + dx) * 768 + 256 + h * 32;
                #pragma unroll
                for (int c8 = 0; c8 < 4; ++c8) {
                    bf16x8 v = *(const bf16x8*)(kp + c8 * 8);
                    #pragma unroll
                    for (int j = 0; j < 8; ++j) a += qv[c8 * 8 + j] * bf2f((unsigned short)v[j]);
                }
            } else {
                const float* pk = pads + h * 32;
                #pragma unroll
                for (int j = 0; j < 32; ++j) a += qv[j] * pk[j];
            }
            sc[t9] = a;
        }
        float m = sc[0];
        #pragma unroll
        for (int t9 = 1; t9 < 9; ++t9) m = fmaxf(m, sc[t9]);
        float s = 0.f;
        #pragma unroll
        for (int t9 = 0; t9 < 9; ++t9) { sc[t9] = __expf(sc[t9] - m); s += sc[t9]; }
        float inv = 1.0f / s;

        float ov[32];
        #pragma unroll
        for (int j = 0; j < 32; ++j) ov[j] = 0.f;
        #pragma unroll
        for (int t9 = 0; t9 < 9; ++t9) {
            int dy = t9 / 3 - 1, dx = t9 % 3 - 1;
            int hh = hh0 + dy, ww = ww0 + dx;
            bool ok = ((unsigned)hh < 64u) && ((unsigned)ww < 64u);
            float w = sc[t9] * inv;
            if (ok) {
                const unsigned short* vp = qkvbf + (size_t)(n + dy * 64 + dx) * 768 + 512 + h * 32;
                #pragma unroll
                for (int c8 = 0; c8 < 4; ++c8) {
                    bf16x8 v = *(const bf16x8*)(vp + c8 * 8);
                    #pragma unroll
                    for (int j = 0; j < 8; ++j) ov[c8 * 8 + j] += w * bf2f((unsigned short)v[j]);
                }
            } else {
                const float* pv = pads + 256 + h * 32;
                #pragma unroll
                for (int j = 0; j < 32; ++j) ov[j] += w * pv[j];
            }
        }
        #pragma unroll
        for (int c8 = 0; c8 < 4; ++c8) {
            u16x8 o8;
            #pragma unroll
            for (int j = 0; j < 8; ++j) o8[j] = f2bf(ov[c8 * 8 + j]);
            *(u16x8*)(Bt + pix * 264 + h * 32 + c8 * 8) = o8;
        }
    }
    __syncthreads();

    // ---- phase 2: GEMM 256ch x 64pix x 256k ----
    int lane = t & 63, wv = t >> 6;          // 8 waves, wave = 32 ch x 64 pix
    int lr = lane & 15, lg = lane >> 4;
    f32x4 acc[2][4] = {};
    for (int k0 = 0; k0 < 256; k0 += 64) {
        if (k0) __syncthreads();
        stage64(Wbf + k0, As, t);            // 256 rows x 64 k
        __syncthreads();
        #pragma unroll
        for (int kk = 0; kk < 2; ++kk) {
            bf16x8 a[2], bb[4];
            #pragma unroll
            for (int i = 0; i < 2; ++i)
                a[i] = *(bf16x8*)(As + (wv * 32 + i * 16 + lr) * 64 + kk * 32 + lg * 8);
            #pragma unroll
            for (int j = 0; j < 4; ++j)
                bb[j] = *(bf16x8*)(Bt + (j * 16 + lr) * 264 + k0 + kk * 32 + lg * 8);
            #pragma unroll
            for (int i = 0; i < 2; ++i)
                #pragma unroll
                for (int j = 0; j < 4; ++j)
                    acc[i][j] = __builtin_amdgcn_mfma_f32_16x16x32_bf16(
                        a[i], bb[j], acc[i][j], 0, 0, 0);
        }
    }
    #pragma unroll
    for (int i = 0; i < 2; ++i) {
        #pragma unroll
        for (int r = 0; r < 4; ++r) {
            int dg = wv * 32 + i * 16 + lg * 4 + r;
            float bd = bias[dg];
            #pragma unroll
            for (int j = 0; j < 4; ++j) {
                int ng = p0 + j * 16 + lr;
                size_t idx = ((size_t)(b * CDIM + dg)) * HW + ng;
                out[idx] = acc[i][j][r] + bd + src[idx];
            }
        }
    }
}

extern "C" void kernel_launch(void* const* d_in, const int* in_sizes, int n_in,
                              void* d_out, int out_size, void* d_ws, size_t ws_size,
                              hipStream_t stream) {
    const float* src  = (const float*)d_in[0];
    const float* lnw  = (const float*)d_in[1];
    const float* lnb  = (const float*)d_in[2];
    const float* Wqkv = (const float*)d_in[3];
    const float* bqkv = (const float*)d_in[4];
    const float* Wout = (const float*)d_in[5];
    const float* bout = (const float*)d_in[6];
    float* out = (float*)d_out;

    unsigned short* x2bf   = (unsigned short*)d_ws;               // 16384*256
    unsigned short* qkvbf  = x2bf  + (size_t)NPIX * CDIM;         // 16384*768
    unsigned short* Wqkvbf = qkvbf + (size_t)NPIX * 768;          // 768*256
    unsigned short* Woutbf = Wqkvbf + 768 * 256;                  // 256*256
    float* pads = (float*)(Woutbf + 256 * 256);                   // 512 floats

    k_prep<<<1026, 256, 0, stream>>>(Wqkv, Wout, bqkv, lnb, Wqkvbf, Woutbf, pads);
    k_ln_t<<<NPIX / 32, 256, 0, stream>>>(src, lnw, lnb, x2bf);
    k_gemm_qkv<<<768, 256, 0, stream>>>(x2bf, Wqkvbf, bqkv, qkvbf);
    k_attn_proj<<<NPIX / 64, 512, 0, stream>>>(qkvbf, pads, Woutbf, bout, src, out);
}